// Round 8
// baseline (494.032 us; speedup 1.0000x reference)
//
#include <hip/hip_runtime.h>

// NeuralODE: z0 = enc(y0); 100 x Tsit5 steps of f = W3 tanh(W2 tanh(W1 y + b1) + b2) + b3;
// outputs ys = dec(z_t), zs = z_t.  One wave (64 thr) per 16 batch elements, grid 256.
//
// === u-space algebra (round 3) ===
// Track u = TS*(W1 y + b1) (32-dim).  M = TS*W1*W3 (32x32 fused), c0 = TS*W1*b3.
// Per stage: h1=tanh(p); q=TSW2 h1+TSb2; h2=tanh(q); m=M h2; running accumulators
// U,P3..P6 build stage inputs.  z materialized once per step (W3*H + dt*b3), H=sum dtB_i h2_i.
//
// === Schedule-length reduction (this revision; re-run — infra failure last round) ===
// Model from r1-r6: wall = in-order schedule length of the serial chain; the dominant
// chain term is tanh's quarter-rate trans issue (16 trans ops = 128 cy per 8-value
// block), during which VALU/MFMA sit idle.  Fixes:
//  - K16 MFMA split (mfma_f32_16x16x16f16): kappa frag slots 0-3 ARE the k<16 half,
//    slots 4-7 the k>=16 half, C/D layout unchanged -> tile-1 tanh overlaps tile-0 MFMAs.
//  - 4 filler slots per stage (inside each tanh-trans window) carry the previous
//    stage's Butcher/H/U/P updates and the whole z-materialize+decode+store of step
//    s-1 (stage-1/2 windows).  First-iteration Z is made exact by H=0, zf=z0-dt*b3.
//  - scalar splits (compiler fuses lo = (f16)(x - (f32)hi) to v_fma_mixlo_f16).
//
// GEMM orientation: D[row, elem] = W[row, k] * Act[k, elem].  Lane l = (e=l&15, q=l>>4).
// C/D: lane holds rows p = 16t+4q+r.  Consumer weight k-columns pre-shuffled by kappa so
// producer C/D registers ARE the consumer's lane-local B-fragment:
// A-frag slot j <- W[row][16*(j>>2)+4*q+(j&3)].  3-term f16 hi/lo split
// (Whi*Bhi+Wlo*Bhi+Whi*Blo) keeps per-product error ~2^-22; m stays f32.

typedef __attribute__((ext_vector_type(8))) _Float16 half8;
typedef __attribute__((ext_vector_type(4))) _Float16 half4;
typedef __attribute__((ext_vector_type(4))) float f32x4;

static constexpr int TN = 101;
static constexpr int BN = 4096;

#define MFMA(a, b, c) __builtin_amdgcn_mfma_f32_16x16x32_f16((a), (b), (c), 0, 0, 0)
#define MFMA16(a, b, c) __builtin_amdgcn_mfma_f32_16x16x16f16((a), (b), (c), 0, 0, 0)

__device__ __forceinline__ float tanh_pre(float x) {
  // input already scaled by 2/ln2: tanh = 1 - 2/(1+2^x); exact at +/-inf via exp2 range.
  float e = __builtin_amdgcn_exp2f(x);
  float r = __builtin_amdgcn_rcpf(e + 1.0f);
  return __builtin_fmaf(-2.0f, r, 1.0f);
}

__device__ __forceinline__ void split8(const float* v, half8& hi, half8& lo) {
#pragma unroll
  for (int j = 0; j < 8; ++j) {
    _Float16 h = (_Float16)v[j];
    hi[j] = h;
    lo[j] = (_Float16)(v[j] - (float)h);  // exact residual; fuses to v_fma_mixlo_f16
  }
}

__device__ __forceinline__ void split4(const float* v, half4& hi, half4& lo) {
#pragma unroll
  for (int j = 0; j < 4; ++j) {
    _Float16 h = (_Float16)v[j];
    hi[j] = h;
    lo[j] = (_Float16)(v[j] - (float)h);
  }
}

__device__ __forceinline__ half4 lo4(half8 v) { return __builtin_shufflevector(v, v, 0, 1, 2, 3); }
__device__ __forceinline__ half4 hi4(half8 v) { return __builtin_shufflevector(v, v, 4, 5, 6, 7); }

// A-fragment for a weight whose k-columns are consumed kappa-shuffled:
// slot j of lane q, K-tile kt  <-  W[row][kt*32 + 16*(j>>2) + 4*q + (j&3)] * scale
__device__ __forceinline__ void load_wfrag(const float* __restrict__ W, int C, int row, int q,
                                           int kt, float scale, half8& hi, half8& lo) {
  const float* p = W + row * C + kt * 32 + 4 * q;
  float v[8] __attribute__((aligned(16)));
  *(f32x4*)(v) = *(const f32x4*)(p);
  *(f32x4*)(v + 4) = *(const f32x4*)(p + 16);
#pragma unroll
  for (int j = 0; j < 8; ++j) v[j] *= scale;
  split8(v, hi, lo);
}

__global__ __launch_bounds__(64, 1) void node_kernel(
    const float* __restrict__ ts, const float* __restrict__ y0,
    const float* __restrict__ encW, const float* __restrict__ encb,
    const float* __restrict__ W1, const float* __restrict__ b1,
    const float* __restrict__ W2, const float* __restrict__ b2,
    const float* __restrict__ W3, const float* __restrict__ b3,
    const float* __restrict__ decW, const float* __restrict__ decb,
    float* __restrict__ out) {
  const int l = threadIdx.x;
  const int lm = l & 15;
  const int q = l >> 4;
  const int eg = blockIdx.x * 16 + lm;

  const float TS = 2.8853900817779268f;  // 2/ln2

  // ---- dt and dt-folded Butcher coefficients ----
  const float dt = (ts[TN - 1] - ts[0]) / (float)(TN - 1);
  const float c21 = dt * 0.161f;
  const float c31 = dt * -0.008480655492356989f, c32 = dt * 0.335480655492357f;
  const float c41 = dt * 2.8971530571054935f, c42 = dt * -6.359448489975075f,
              c43 = dt * 4.3622954328695815f;
  const float c51 = dt * 5.325864828439257f, c52 = dt * -11.748883564062828f,
              c53 = dt * 7.4955393428898365f, c54 = dt * -0.09249506636175525f;
  const float c61 = dt * 5.86145544294642f, c62 = dt * -12.92096931784711f,
              c63 = dt * 8.159367898576159f, c64 = dt * -0.071584973281401f,
              c65 = dt * -0.028269050394068383f;
  const float d1 = dt * 0.09646076681806523f, d2 = dt * 0.01f, d3 = dt * 0.4798896504144996f,
              d4 = dt * 1.379008574103742f, d5 = dt * -3.290069515436081f,
              d6 = dt * 2.324710524099774f;
  const float sg3 = dt * 0.327f, sg4 = dt * 0.9f, sg5 = dt * 0.9800255409045097f,
              sg6 = dt * 1.0f;

  // ---- persistent weight fragments ----
  half8 w2h8[2], w2l8[2], w3h[4], w3l[4];
#pragma unroll
  for (int mt = 0; mt < 2; ++mt) load_wfrag(W2, 32, 16 * mt + lm, q, 0, TS, w2h8[mt], w2l8[mt]);
#pragma unroll
  for (int mt = 0; mt < 4; ++mt) load_wfrag(W3, 32, 16 * mt + lm, q, 0, 1.0f, w3h[mt], w3l[mt]);

  half4 w2h4[2][2], w2l4[2][2];
#pragma unroll
  for (int mt = 0; mt < 2; ++mt) {
    w2h4[mt][0] = lo4(w2h8[mt]);
    w2h4[mt][1] = hi4(w2h8[mt]);
    w2l4[mt][0] = lo4(w2l8[mt]);
    w2l4[mt][1] = hi4(w2l8[mt]);
  }

  f32x4 b2f[2], db3f[4];
#pragma unroll
  for (int mt = 0; mt < 2; ++mt) {
    f32x4 t2 = *(const f32x4*)(b2 + 16 * mt + 4 * q);
#pragma unroll
    for (int r = 0; r < 4; ++r) t2[r] *= TS;
    b2f[mt] = t2;
  }
#pragma unroll
  for (int mt = 0; mt < 4; ++mt) {
    f32x4 t3 = *(const f32x4*)(b3 + 16 * mt + 4 * q);
#pragma unroll
    for (int r = 0; r < 4; ++r) t3[r] *= dt;
    db3f[mt] = t3;
  }

  // ---- decoder frags in registers (single f16: decoder error does not feed back) ----
  half8 dech[4][2];
  f32x4 decbf[4];
#pragma unroll
  for (int mt = 0; mt < 4; ++mt) {
#pragma unroll
    for (int kt = 0; kt < 2; ++kt) {
      const float* p = decW + (16 * mt + lm) * 64 + kt * 32 + 4 * q;
      float v[8] __attribute__((aligned(16)));
      *(f32x4*)(v) = *(const f32x4*)(p);
      *(f32x4*)(v + 4) = *(const f32x4*)(p + 16);
      half8 h;
#pragma unroll
      for (int j = 0; j < 8; ++j) h[j] = (_Float16)v[j];
      dech[mt][kt] = h;
    }
    decbf[mt] = *(const f32x4*)(decb + 16 * mt + 4 * q);
  }

  // ---- fused M = TS * W1 * W3 (A-frag layout, f32 dots -> hi/lo split) ----
  half4 Mh4[2][2], Ml4[2][2];
  {
    float Mv0[8] = {0, 0, 0, 0, 0, 0, 0, 0};
    float Mv1[8] = {0, 0, 0, 0, 0, 0, 0, 0};
    const float* w1a = W1 + (size_t)lm * 64;
    const float* w1b = W1 + (size_t)(16 + lm) * 64;
    for (int k = 0; k < 64; ++k) {
      float a = w1a[k], b = w1b[k];
      const float* w3r = W3 + (size_t)k * 32 + 4 * q;
#pragma unroll
      for (int jj = 0; jj < 2; ++jj) {
#pragma unroll
        for (int r = 0; r < 4; ++r) {
          float w3v = w3r[16 * jj + r];
          Mv0[4 * jj + r] = __builtin_fmaf(a, w3v, Mv0[4 * jj + r]);
          Mv1[4 * jj + r] = __builtin_fmaf(b, w3v, Mv1[4 * jj + r]);
        }
      }
    }
#pragma unroll
    for (int j = 0; j < 8; ++j) {
      Mv0[j] *= TS;
      Mv1[j] *= TS;
    }
    half8 Mh8, Ml8;
    split8(Mv0, Mh8, Ml8);
    Mh4[0][0] = lo4(Mh8);
    Mh4[0][1] = hi4(Mh8);
    Ml4[0][0] = lo4(Ml8);
    Ml4[0][1] = hi4(Ml8);
    split8(Mv1, Mh8, Ml8);
    Mh4[1][0] = lo4(Mh8);
    Mh4[1][1] = hi4(Mh8);
    Ml4[1][0] = lo4(Ml8);
    Ml4[1][1] = hi4(Ml8);
  }

  // ---- c0 = TS * W1 * b3 in C/D layout: rows 16*mt + 4*q + r ----
  float c0[8] = {0, 0, 0, 0, 0, 0, 0, 0};
  {
    for (int k = 0; k < 64; ++k) {
      float bk = b3[k];
#pragma unroll
      for (int mt = 0; mt < 2; ++mt)
#pragma unroll
        for (int r = 0; r < 4; ++r)
          c0[4 * mt + r] =
              __builtin_fmaf(W1[(size_t)(16 * mt + 4 * q + r) * 64 + k], bk, c0[4 * mt + r]);
    }
#pragma unroll
    for (int j = 0; j < 8; ++j) c0[j] *= TS;
  }

  // ---- encoder: z0 = encW * y0^T + encb ----
  f32x4 zf[4];
  {
    const float* yp = y0 + (size_t)eg * 64;
    float v[16] __attribute__((aligned(16)));
    *(f32x4*)(v) = *(const f32x4*)(yp + 8 * q);
    *(f32x4*)(v + 4) = *(const f32x4*)(yp + 8 * q + 4);
    *(f32x4*)(v + 8) = *(const f32x4*)(yp + 32 + 8 * q);
    *(f32x4*)(v + 12) = *(const f32x4*)(yp + 32 + 8 * q + 4);
    half8 xh[2], xl[2];
    split8(v, xh[0], xl[0]);
    split8(v + 8, xh[1], xl[1]);
#pragma unroll
    for (int mt = 0; mt < 4; ++mt) {
      const float* p0 = encW + (16 * mt + lm) * 64 + 8 * q;
      float w[8] __attribute__((aligned(16)));
      half8 eh, el;
      f32x4 a = *(const f32x4*)(encb + 16 * mt + 4 * q);
      *(f32x4*)(w) = *(const f32x4*)(p0);
      *(f32x4*)(w + 4) = *(const f32x4*)(p0 + 4);
      split8(w, eh, el);
      a = MFMA(eh, xh[0], a);
      a = MFMA(el, xh[0], a);
      a = MFMA(eh, xl[0], a);
      *(f32x4*)(w) = *(const f32x4*)(p0 + 32);
      *(f32x4*)(w + 4) = *(const f32x4*)(p0 + 36);
      split8(w, eh, el);
      a = MFMA(eh, xh[1], a);
      a = MFMA(el, xh[1], a);
      a = MFMA(eh, xl[1], a);
      zf[mt] = a;
    }
  }

  // ---- u0 = TS*(W1 z0 + b1) via transient L1 pass ----
  float u[8];
  {
    half8 t1h[2][2], t1l[2][2];
    f32x4 tb1[2];
#pragma unroll
    for (int mt = 0; mt < 2; ++mt) {
#pragma unroll
      for (int kt = 0; kt < 2; ++kt)
        load_wfrag(W1, 64, 16 * mt + lm, q, kt, TS, t1h[mt][kt], t1l[mt][kt]);
      f32x4 t1 = *(const f32x4*)(b1 + 16 * mt + 4 * q);
#pragma unroll
      for (int r = 0; r < 4; ++r) t1[r] *= TS;
      tb1[mt] = t1;
    }
    float zv[16];
#pragma unroll
    for (int mt = 0; mt < 4; ++mt)
#pragma unroll
      for (int r = 0; r < 4; ++r) zv[4 * mt + r] = zf[mt][r];
    half8 yh[2], yl[2];
    split8(zv, yh[0], yl[0]);
    split8(zv + 8, yh[1], yl[1]);
#pragma unroll
    for (int mt = 0; mt < 2; ++mt) {
      f32x4 a = tb1[mt];
      a = MFMA(t1h[mt][0], yh[0], a);
      a = MFMA(t1l[mt][0], yh[0], a);
      a = MFMA(t1h[mt][0], yl[0], a);
      a = MFMA(t1h[mt][1], yh[1], a);
      a = MFMA(t1l[mt][1], yh[1], a);
      a = MFMA(t1h[mt][1], yl[1], a);
#pragma unroll
      for (int r = 0; r < 4; ++r) u[4 * mt + r] = a[r];
    }
  }

  // ---- output helpers (read zf) ----
  auto store_z = [&](int s) {
    float* zb = out + (size_t)BN * TN * 64 + ((size_t)eg * TN + s) * 64;
#pragma unroll
    for (int mt = 0; mt < 4; ++mt) *(f32x4*)(zb + 16 * mt + 4 * q) = zf[mt];
  };
  auto dec_store = [&](int s) {
    half8 xh[2];
#pragma unroll
    for (int j = 0; j < 4; ++j) {
      xh[0][j] = (_Float16)zf[0][j];
      xh[0][4 + j] = (_Float16)zf[1][j];
      xh[1][j] = (_Float16)zf[2][j];
      xh[1][4 + j] = (_Float16)zf[3][j];
    }
    float* yb = out + ((size_t)eg * TN + s) * 64;
#pragma unroll
    for (int mt = 0; mt < 4; ++mt) {
      f32x4 a = decbf[mt];
      a = MFMA(dech[mt][0], xh[0], a);
      a = MFMA(dech[mt][1], xh[1], a);
      *(f32x4*)(yb + 16 * mt + 4 * q) = a;
    }
  };

  // ---- per-stage core with K16 MFMAs and 4 filler windows (inside tanh trans issue) ----
  auto LC = [&](const float (&pin)[8], float (&h2o)[8], float (&mo)[8], auto&& F0, auto&& F1,
                auto&& F2, auto&& F3) {
    float ha[4], hb[4];
    half4 hah, hal, hbh, hbl;
#pragma unroll
    for (int j = 0; j < 4; ++j) ha[j] = tanh_pre(pin[j]);
    F0();  // window 0: filler issues while trans pipe drains
    split4(ha, hah, hal);
#pragma unroll
    for (int j = 0; j < 4; ++j) hb[j] = tanh_pre(pin[4 + j]);
    F1();  // window 1
    split4(hb, hbh, hbl);
    float qv[8];
#pragma unroll
    for (int mt = 0; mt < 2; ++mt) {
      f32x4 a = b2f[mt];
      a = MFMA16(w2h4[mt][0], hah, a);  // k<16: Whi*Bhi
      a = MFMA16(w2l4[mt][0], hah, a);  //        Wlo*Bhi
      a = MFMA16(w2h4[mt][0], hal, a);  //        Whi*Blo
      a = MFMA16(w2h4[mt][1], hbh, a);  // k>=16
      a = MFMA16(w2l4[mt][1], hbh, a);
      a = MFMA16(w2h4[mt][1], hbl, a);
#pragma unroll
      for (int r = 0; r < 4; ++r) qv[4 * mt + r] = a[r];
    }
    half4 th0, tl0, th1, tl1;
#pragma unroll
    for (int j = 0; j < 4; ++j) h2o[j] = tanh_pre(qv[j]);
    F2();  // window 2
    split4(h2o, th0, tl0);
#pragma unroll
    for (int j = 0; j < 4; ++j) h2o[4 + j] = tanh_pre(qv[4 + j]);
    F3();  // window 3
    split4(h2o + 4, th1, tl1);
#pragma unroll
    for (int mt = 0; mt < 2; ++mt) {
      f32x4 a = {0.0f, 0.0f, 0.0f, 0.0f};
      a = MFMA16(Mh4[mt][0], th0, a);
      a = MFMA16(Ml4[mt][0], th0, a);
      a = MFMA16(Mh4[mt][0], tl0, a);
      a = MFMA16(Mh4[mt][1], th1, a);
      a = MFMA16(Ml4[mt][1], th1, a);
      a = MFMA16(Mh4[mt][1], tl1, a);
#pragma unroll
      for (int r = 0; r < 4; ++r) mo[4 * mt + r] = a[r];
    }
  };

  // ---- prologue: H=0, zf = z0 - dt*b3 makes the first in-loop Z produce exactly z0 ----
  float H[8];
#pragma unroll
  for (int j = 0; j < 8; ++j) H[j] = 0.0f;
#pragma unroll
  for (int mt = 0; mt < 4; ++mt) zf[mt] = zf[mt] - db3f[mt];

#pragma nounroll
  for (int s = 1; s < TN; ++s) {
    float U[8], P3[8], P4[8], P5[8], P6[8], pv[8], mA[8], mB[8], h2A[8], h2B[8];
    half8 Hh, Hl;
    // ---- stage 1: fillers = Z(s-1) [prev-step z materialize + store + decode] + inits ----
    LC(u, h2A, mA,
       [&] {
         split8(H, Hh, Hl);
#pragma unroll
         for (int j = 0; j < 8; ++j) {
           U[j] = __builtin_fmaf(dt, c0[j], u[j]);
           P3[j] = __builtin_fmaf(sg3, c0[j], u[j]);
         }
       },
       [&] {
#pragma unroll
         for (int mt = 0; mt < 2; ++mt) {
           f32x4 a = zf[mt];
           a = MFMA(w3h[mt], Hh, a);
           a = MFMA(w3l[mt], Hh, a);
           a = MFMA(w3h[mt], Hl, a);
           zf[mt] = a + db3f[mt];
         }
#pragma unroll
         for (int j = 0; j < 8; ++j) {
           P4[j] = __builtin_fmaf(sg4, c0[j], u[j]);
           P5[j] = __builtin_fmaf(sg5, c0[j], u[j]);
         }
       },
       [&] {
#pragma unroll
         for (int mt = 2; mt < 4; ++mt) {
           f32x4 a = zf[mt];
           a = MFMA(w3h[mt], Hh, a);
           a = MFMA(w3l[mt], Hh, a);
           a = MFMA(w3h[mt], Hl, a);
           zf[mt] = a + db3f[mt];
         }
#pragma unroll
         for (int j = 0; j < 8; ++j) P6[j] = __builtin_fmaf(sg6, c0[j], u[j]);
         store_z(s - 1);
       },
       [&] { dec_store(s - 1); });
#pragma unroll
    for (int j = 0; j < 8; ++j) pv[j] = __builtin_fmaf(c21, c0[j] + mA[j], u[j]);  // sig2==c21
    // ---- stage 2: fillers = carry of stage 1 ----
    LC(pv, h2B, mB,
       [&] {
#pragma unroll
         for (int j = 0; j < 8; ++j) {
           H[j] = d1 * h2A[j];
           U[j] = __builtin_fmaf(d1, mA[j], U[j]);
         }
       },
       [&] {
#pragma unroll
         for (int j = 0; j < 8; ++j) {
           P3[j] = __builtin_fmaf(c31, mA[j], P3[j]);
           P4[j] = __builtin_fmaf(c41, mA[j], P4[j]);
         }
       },
       [&] {
#pragma unroll
         for (int j = 0; j < 8; ++j) P5[j] = __builtin_fmaf(c51, mA[j], P5[j]);
       },
       [&] {
#pragma unroll
         for (int j = 0; j < 8; ++j) P6[j] = __builtin_fmaf(c61, mA[j], P6[j]);
       });
#pragma unroll
    for (int j = 0; j < 8; ++j) pv[j] = __builtin_fmaf(c32, mB[j], P3[j]);
    // ---- stage 3: carry of stage 2 ----
    LC(pv, h2A, mA,
       [&] {
#pragma unroll
         for (int j = 0; j < 8; ++j) {
           H[j] = __builtin_fmaf(d2, h2B[j], H[j]);
           U[j] = __builtin_fmaf(d2, mB[j], U[j]);
         }
       },
       [&] {
#pragma unroll
         for (int j = 0; j < 8; ++j) {
           P4[j] = __builtin_fmaf(c42, mB[j], P4[j]);
           P5[j] = __builtin_fmaf(c52, mB[j], P5[j]);
         }
       },
       [&] {
#pragma unroll
         for (int j = 0; j < 8; ++j) P6[j] = __builtin_fmaf(c62, mB[j], P6[j]);
       },
       [&] {});
#pragma unroll
    for (int j = 0; j < 8; ++j) pv[j] = __builtin_fmaf(c43, mA[j], P4[j]);
    // ---- stage 4: carry of stage 3 ----
    LC(pv, h2B, mB,
       [&] {
#pragma unroll
         for (int j = 0; j < 8; ++j) {
           H[j] = __builtin_fmaf(d3, h2A[j], H[j]);
           U[j] = __builtin_fmaf(d3, mA[j], U[j]);
         }
       },
       [&] {
#pragma unroll
         for (int j = 0; j < 8; ++j) {
           P5[j] = __builtin_fmaf(c53, mA[j], P5[j]);
           P6[j] = __builtin_fmaf(c63, mA[j], P6[j]);
         }
       },
       [&] {}, [&] {});
#pragma unroll
    for (int j = 0; j < 8; ++j) pv[j] = __builtin_fmaf(c54, mB[j], P5[j]);
    // ---- stage 5: carry of stage 4 ----
    LC(pv, h2A, mA,
       [&] {
#pragma unroll
         for (int j = 0; j < 8; ++j) {
           H[j] = __builtin_fmaf(d4, h2B[j], H[j]);
           U[j] = __builtin_fmaf(d4, mB[j], U[j]);
         }
       },
       [&] {
#pragma unroll
         for (int j = 0; j < 8; ++j) P6[j] = __builtin_fmaf(c64, mB[j], P6[j]);
       },
       [&] {}, [&] {});
#pragma unroll
    for (int j = 0; j < 8; ++j) pv[j] = __builtin_fmaf(c65, mA[j], P6[j]);
    // ---- stage 6: carry of stage 5 ----
    LC(pv, h2B, mB,
       [&] {
#pragma unroll
         for (int j = 0; j < 8; ++j) {
           H[j] = __builtin_fmaf(d5, h2A[j], H[j]);
           U[j] = __builtin_fmaf(d5, mA[j], U[j]);
         }
       },
       [&] {}, [&] {}, [&] {});
    // ---- on-path tail: finalize H and u (needed before next iteration's stage 1) ----
#pragma unroll
    for (int j = 0; j < 8; ++j) {
      H[j] = __builtin_fmaf(d6, h2B[j], H[j]);
      u[j] = __builtin_fmaf(d6, mB[j], U[j]);
    }
  }

  // ---- final z materialization + outputs for step TN-1 ----
  {
    half8 Hh, Hl;
    split8(H, Hh, Hl);
#pragma unroll
    for (int mt = 0; mt < 4; ++mt) {
      f32x4 a = zf[mt];
      a = MFMA(w3h[mt], Hh, a);
      a = MFMA(w3l[mt], Hh, a);
      a = MFMA(w3h[mt], Hl, a);
      zf[mt] = a + db3f[mt];
    }
    store_z(TN - 1);
    dec_store(TN - 1);
  }
}

extern "C" void kernel_launch(void* const* d_in, const int* in_sizes, int n_in,
                              void* d_out, int out_size, void* d_ws, size_t ws_size,
                              hipStream_t stream) {
  const float* ts = (const float*)d_in[0];
  const float* y0 = (const float*)d_in[1];
  const float* encW = (const float*)d_in[2];
  const float* encb = (const float*)d_in[3];
  const float* W1 = (const float*)d_in[4];
  const float* b1 = (const float*)d_in[5];
  const float* W2 = (const float*)d_in[6];
  const float* b2 = (const float*)d_in[7];
  const float* W3 = (const float*)d_in[8];
  const float* b3 = (const float*)d_in[9];
  const float* decW = (const float*)d_in[10];
  const float* decb = (const float*)d_in[11];
  node_kernel<<<BN / 16, 64, 0, stream>>>(ts, y0, encW, encb, W1, b1, W2, b2, W3, b3, decW,
                                          decb, (float*)d_out);
}